// Round 17
// baseline (22.611 us; speedup 1.0000x reference)
//
#include <hip/hip_runtime.h>

#define NS 8192
#define MS 2048
#define DD 32
#define MSPLIT 32
#define MCH 64        // m per block
#define NITS 4        // m-tiles per block
#define RBLK 32       // reduce blocks

typedef __attribute__((ext_vector_type(8))) short bf16x8;
typedef __attribute__((ext_vector_type(4))) float f32x4;
typedef unsigned short u16;
typedef unsigned int u32;

// ws byte offsets
#define PART_OFF 0                          // [MSPLIT][NS] f32 (1 MB)
#define MM_OFF   (MSPLIT * NS * 4)          // 2 u32 (min,max bits)
#define CNT_OFF  (MM_OFF + 8)               // 1 u32

__device__ inline float fast_exp2(float x) {
#if __has_builtin(__builtin_amdgcn_exp2f)
    return __builtin_amdgcn_exp2f(x);
#else
    return exp2f(x);
#endif
}

__device__ inline u32 cvt_pk_bf16(float a, float b) {
    u32 r;
    asm("v_cvt_pk_bf16_f32 %0, %1, %2" : "=v"(r) : "v"(a), "v"(b));
    return r;
}

// Split 8 floats into hi/lo bf16x8 (RNE). Pack-order safe: X and W use the
// same helper, so MFMA dots pair identical k-elements either way.
__device__ inline void split8(const float* v, bf16x8& hi, bf16x8& lo) {
    union { u32 u[4]; bf16x8 b; } H, L;
#pragma unroll
    for (int j = 0; j < 4; ++j) {
        u32 h = cvt_pk_bf16(v[2 * j], v[2 * j + 1]);
        float ha = __uint_as_float(h << 16);
        float hb = __uint_as_float(h & 0xFFFF0000u);
        L.u[j] = cvt_pk_bf16(v[2 * j] - ha, v[2 * j + 1] - hb);
        H.u[j] = h;
    }
    hi = H.b;
    lo = L.b;
}

// R16 body restructured nt-outer/it-inner: only ONE n-tile's X fragments live
// at a time (16 VGPR vs 64) -> peak live ~80 fits the (256,5) cap of ~100.
// 5 blocks/CU = 20 waves/CU (+25% TLP over R16's 16): R8's direct profile
// showed this kernel latency-stalled (Occ 34%, MFMA 22%, VALU 22%).
// "#pragma unroll 1" on the nt loop is LOAD-BEARING: full unroll would hoist
// all 4 conversions and restore the 64-reg X set.
__global__ __launch_bounds__(256, 5) void kde_fused(const float* __restrict__ samples,
                                                    const float* __restrict__ means,
                                                    const float* __restrict__ stds,
                                                    unsigned char* __restrict__ wsb) {
    __shared__ u16 WBH[2048], WBL[2048], WCH[2048], WCL[2048];  // [it][g][r15][8]
    __shared__ float A2s[MCH];

    const int t = threadIdx.x;
    const int m0 = blockIdx.y * MCH;
    const float L2E = 1.4426950408889634f;

    if (blockIdx.x == 0 && blockIdx.y == 0 && t == 0) {
        unsigned* mm = (unsigned*)(wsb + MM_OFF);
        mm[0] = 0x7f7fffffu;  // FLT_MAX bits (uint cmp == float cmp, all positive)
        mm[1] = 0u;
        *(unsigned*)(wsb + CNT_OFF) = 0u;
    }

    // ---- phase 1: W chunk -> LDS, one thread per (m_local, 8-d quarter) ----
    {
        const int ml = t >> 2, qd = t & 3;
        const float* mp = means + (size_t)(m0 + ml) * DD + qd * 8;
        const float* vp = stds  + (size_t)(m0 + ml) * DD + qd * 8;
        float4 a4 = *(const float4*)mp, b4 = *(const float4*)(mp + 4);
        float4 c4 = *(const float4*)vp, d4 = *(const float4*)(vp + 4);
        float mu[8] = {a4.x, a4.y, a4.z, a4.w, b4.x, b4.y, b4.z, b4.w};
        float sd[8] = {c4.x, c4.y, c4.z, c4.w, d4.x, d4.y, d4.z, d4.w};
        float Bv[8], Cv[8], a = 0.f;
#pragma unroll
        for (int j = 0; j < 8; ++j) {
            float inv = 1.0f / sd[j];
            Bv[j] = L2E * mu[j] * inv;
            Cv[j] = -0.5f * L2E * inv;
            a += mu[j] * mu[j] * inv;
        }
        a += __shfl_xor(a, 1);
        a += __shfl_xor(a, 2);
        if (qd == 0) A2s[ml] = -0.5f * L2E * a - 11.0f;  // -log2(M) folds the mean

        bf16x8 bh, bl, ch, cl;
        split8(Bv, bh, bl);
        split8(Cv, ch, cl);
        const int it = ml >> 4, r15 = ml & 15;
        const int base = ((it * 4 + qd) * 16 + r15) * 8;
        *(bf16x8*)&WBH[base] = bh;
        *(bf16x8*)&WBL[base] = bl;
        *(bf16x8*)&WCH[base] = ch;
        *(bf16x8*)&WCL[base] = cl;
    }

    const int lane = t & 63, wid = t >> 6;
    const int r15 = lane & 15, g = lane >> 4;
    const int n0 = blockIdx.x * 256 + wid * 64;

    __syncthreads();

    // ---- phases 2+3 fused, nt-outer: convert one n-tile, sweep all m-tiles ----
    f32x4 rs[4];
#pragma unroll
    for (int nt = 0; nt < 4; ++nt) rs[nt] = (f32x4){0.f, 0.f, 0.f, 0.f};

#pragma unroll 1
    for (int nt = 0; nt < 4; ++nt) {
        const float* sp = samples + (size_t)(n0 + nt * 16 + r15) * DD + g * 8;
        float4 a4 = *(const float4*)sp, b4 = *(const float4*)(sp + 4);
        float xv[8] = {a4.x, a4.y, a4.z, a4.w, b4.x, b4.y, b4.z, b4.w};
        float qv[8];
#pragma unroll
        for (int j = 0; j < 8; ++j) qv[j] = xv[j] * xv[j];
        bf16x8 xh, xl, qh, ql;
        split8(xv, xh, xl);
        split8(qv, qh, ql);

#pragma unroll 2
        for (int it = 0; it < NITS; ++it) {
            const int base = ((it * 4 + g) * 16 + r15) * 8;
            bf16x8 bh = *(const bf16x8*)&WBH[base];
            bf16x8 ch = *(const bf16x8*)&WCH[base];
            bf16x8 bl = *(const bf16x8*)&WBL[base];
            bf16x8 cl = *(const bf16x8*)&WCL[base];
            const float a2 = A2s[it * 16 + r15];
            f32x4 acc = (f32x4){a2, a2, a2, a2};   // col=r15 -> a2 const per lane
            acc = __builtin_amdgcn_mfma_f32_16x16x32_bf16(xh, bh, acc, 0, 0, 0);
            acc = __builtin_amdgcn_mfma_f32_16x16x32_bf16(qh, ch, acc, 0, 0, 0);
            acc = __builtin_amdgcn_mfma_f32_16x16x32_bf16(xl, bh, acc, 0, 0, 0);
            acc = __builtin_amdgcn_mfma_f32_16x16x32_bf16(ql, ch, acc, 0, 0, 0);
            acc = __builtin_amdgcn_mfma_f32_16x16x32_bf16(xh, bl, acc, 0, 0, 0);
            acc = __builtin_amdgcn_mfma_f32_16x16x32_bf16(qh, cl, acc, 0, 0, 0);
#pragma unroll
            for (int r = 0; r < 4; ++r) rs[nt][r] += fast_exp2(acc[r]);
        }
    }

    // sum the 16 m-columns (lanes sharing g)
#pragma unroll
    for (int o = 1; o < 16; o <<= 1)
#pragma unroll
        for (int nt = 0; nt < 4; ++nt)
#pragma unroll
            for (int r = 0; r < 4; ++r) rs[nt][r] += __shfl_xor(rs[nt][r], o);

    float* partial = (float*)(wsb + PART_OFF);
    if (r15 == 0) {
#pragma unroll
        for (int nt = 0; nt < 4; ++nt)
            *(f32x4*)(partial + (size_t)blockIdx.y * NS + n0 + nt * 16 + g * 4) = rs[nt];
    }
}

// Merged reduce+flip (R16, proven): 32 co-resident blocks; dist in registers;
// min/max atomics; counter rendezvous (cnt initialized by kde_fused, ordered
// by the kernel boundary); distributed flip.
__global__ __launch_bounds__(256) void reduce_flip(unsigned char* __restrict__ wsb,
                                                   float* __restrict__ out) {
    const float* partial = (const float*)(wsb + PART_OFF);
    unsigned* mm = (unsigned*)(wsb + MM_OFF);
    unsigned* cnt = (unsigned*)(wsb + CNT_OFF);

    const int tid = threadIdx.x;
    const int n = blockIdx.x * 256 + tid;
    float v = 0.f;
#pragma unroll
    for (int j = 0; j < MSPLIT; ++j) v += partial[(size_t)j * NS + n];

    float mn = v, mx = v;
#pragma unroll
    for (int o = 1; o < 64; o <<= 1) {
        mn = fminf(mn, __shfl_xor(mn, o));
        mx = fmaxf(mx, __shfl_xor(mx, o));
    }
    __shared__ float smn[4], smx[4];
    __shared__ float sres[2];
    const int wv = tid >> 6, ln = tid & 63;
    if (ln == 0) { smn[wv] = mn; smx[wv] = mx; }
    __syncthreads();
    if (tid == 0) {
#pragma unroll
        for (int j = 1; j < 4; ++j) {
            mn = fminf(mn, smn[j]);
            mx = fmaxf(mx, smx[j]);
        }
        atomicMin(mm + 0, __float_as_uint(mn));
        atomicMax(mm + 1, __float_as_uint(mx));
        __threadfence();                       // release our atomics
        atomicAdd(cnt, 1u);
        while (__hip_atomic_load(cnt, __ATOMIC_ACQUIRE, __HIP_MEMORY_SCOPE_AGENT)
               < RBLK) {}
        sres[0] = __uint_as_float(
            __hip_atomic_load(mm + 0, __ATOMIC_RELAXED, __HIP_MEMORY_SCOPE_AGENT));
        sres[1] = __uint_as_float(
            __hip_atomic_load(mm + 1, __ATOMIC_RELAXED, __HIP_MEMORY_SCOPE_AGENT));
    }
    __syncthreads();
    out[n] = sres[1] + sres[0] - v;
}

extern "C" void kernel_launch(void* const* d_in, const int* in_sizes, int n_in,
                              void* d_out, int out_size, void* d_ws, size_t ws_size,
                              hipStream_t stream) {
    const float* samples = (const float*)d_in[0];
    const float* means   = (const float*)d_in[1];
    const float* stds    = (const float*)d_in[2];
    unsigned char* ws = (unsigned char*)d_ws;
    float* out = (float*)d_out;

    kde_fused<<<dim3(NS / 256, MSPLIT), 256, 0, stream>>>(samples, means, stds, ws);
    reduce_flip<<<dim3(RBLK), 256, 0, stream>>>(ws, out);
}

// Round 18
// 20.899 us; speedup vs baseline: 1.0819x; 1.0819x over previous
//
#include <hip/hip_runtime.h>

#define NS 8192
#define MS 2048
#define DD 32
#define MSPLIT 32
#define MCH 64        // m per block
#define NITS 4        // m-tiles per block
#define RBLK 8        // reduce blocks (each 1024 n, f32x4)

typedef __attribute__((ext_vector_type(8))) short bf16x8;
typedef __attribute__((ext_vector_type(4))) float f32x4;
typedef __attribute__((ext_vector_type(2))) float f32x2;
typedef unsigned short u16;
typedef unsigned int u32;

// ws byte offsets
#define PART_OFF 0                          // [MSPLIT][NS] f32 (1 MB)
#define MM_OFF   (MSPLIT * NS * 4)          // 2 u32 (min,max bits)
#define CNT_OFF  (MM_OFF + 8)               // 1 u32

__device__ inline float fast_exp2(float x) {
#if __has_builtin(__builtin_amdgcn_exp2f)
    return __builtin_amdgcn_exp2f(x);
#else
    return exp2f(x);
#endif
}
__device__ inline float fast_rcp(float x) {
#if __has_builtin(__builtin_amdgcn_rcpf)
    return __builtin_amdgcn_rcpf(x);   // 1 inst vs ~8 for exact div (R6-validated)
#else
    return 1.0f / x;
#endif
}

__device__ inline u32 cvt_pk_bf16(float a, float b) {
    u32 r;
    asm("v_cvt_pk_bf16_f32 %0, %1, %2" : "=v"(r) : "v"(a), "v"(b));
    return r;
}

// Split 4x f32x2 into hi/lo bf16x8 (RNE). Vector-form subtraction so hipcc can
// emit packed fp32 (v_pk_add_f32). Pack-order safe: X and W use the same
// helper, so MFMA dots pair identical k-elements either way.
__device__ inline void split8v(const f32x2* v2, bf16x8& hi, bf16x8& lo) {
    union { u32 u[4]; bf16x8 b; } H, L;
#pragma unroll
    for (int j = 0; j < 4; ++j) {
        u32 h = cvt_pk_bf16(v2[j].x, v2[j].y);
        f32x2 hf;
        hf.x = __uint_as_float(h << 16);
        hf.y = __uint_as_float(h & 0xFFFF0000u);
        f32x2 d = v2[j] - hf;
        L.u[j] = cvt_pk_bf16(d.x, d.y);
        H.u[j] = h;
    }
    hi = H.b;
    lo = L.b;
}

// R16 structure (proven 19.19us) with conversion arithmetic in f32x2 form and
// fast_rcp in phase 1. X loads all issue up front (R17 proved serializing them
// behind the nt-loop costs 3us).
__global__ __launch_bounds__(256, 4) void kde_fused(const float* __restrict__ samples,
                                                    const float* __restrict__ means,
                                                    const float* __restrict__ stds,
                                                    unsigned char* __restrict__ wsb) {
    __shared__ u16 WBH[2048], WBL[2048], WCH[2048], WCL[2048];  // [it][g][r15][8]
    __shared__ float A2s[MCH];

    const int t = threadIdx.x;
    const int m0 = blockIdx.y * MCH;
    const float L2E = 1.4426950408889634f;

    if (blockIdx.x == 0 && blockIdx.y == 0 && t == 0) {
        unsigned* mm = (unsigned*)(wsb + MM_OFF);
        mm[0] = 0x7f7fffffu;  // FLT_MAX bits (uint cmp == float cmp, all positive)
        mm[1] = 0u;
        *(unsigned*)(wsb + CNT_OFF) = 0u;
    }

    // ---- phase 1: W chunk -> LDS, one thread per (m_local, 8-d quarter) ----
    {
        const int ml = t >> 2, qd = t & 3;
        const float* mp = means + (size_t)(m0 + ml) * DD + qd * 8;
        const float* vp = stds  + (size_t)(m0 + ml) * DD + qd * 8;
        float4 a4 = *(const float4*)mp, b4 = *(const float4*)(mp + 4);
        float4 c4 = *(const float4*)vp, d4 = *(const float4*)(vp + 4);
        f32x2 mu2[4] = {{a4.x, a4.y}, {a4.z, a4.w}, {b4.x, b4.y}, {b4.z, b4.w}};
        f32x2 sd2[4] = {{c4.x, c4.y}, {c4.z, c4.w}, {d4.x, d4.y}, {d4.z, d4.w}};
        f32x2 Bv2[4], Cv2[4], acc2 = {0.f, 0.f};
#pragma unroll
        for (int j = 0; j < 4; ++j) {
            f32x2 inv;
            inv.x = fast_rcp(sd2[j].x);
            inv.y = fast_rcp(sd2[j].y);
            Bv2[j] = (L2E * mu2[j]) * inv;
            Cv2[j] = (-0.5f * L2E) * inv;
            acc2 += (mu2[j] * mu2[j]) * inv;
        }
        float a = acc2.x + acc2.y;
        a += __shfl_xor(a, 1);
        a += __shfl_xor(a, 2);
        if (qd == 0) A2s[ml] = -0.5f * L2E * a - 11.0f;  // -log2(M) folds the mean

        bf16x8 bh, bl, ch, cl;
        split8v(Bv2, bh, bl);
        split8v(Cv2, ch, cl);
        const int it = ml >> 4, r15 = ml & 15;
        const int base = ((it * 4 + qd) * 16 + r15) * 8;
        *(bf16x8*)&WBH[base] = bh;
        *(bf16x8*)&WBL[base] = bl;
        *(bf16x8*)&WCH[base] = ch;
        *(bf16x8*)&WCL[base] = cl;
    }

    // ---- phase 2: X fragments straight from samples (all 4 tiles up front) ----
    const int lane = t & 63, wid = t >> 6;
    const int r15 = lane & 15, g = lane >> 4;
    const int n0 = blockIdx.x * 256 + wid * 64;

    bf16x8 xh[4], xl[4], qh[4], ql[4];
#pragma unroll
    for (int nt = 0; nt < 4; ++nt) {
        const float* sp = samples + (size_t)(n0 + nt * 16 + r15) * DD + g * 8;
        float4 a4 = *(const float4*)sp, b4 = *(const float4*)(sp + 4);
        f32x2 xv2[4] = {{a4.x, a4.y}, {a4.z, a4.w}, {b4.x, b4.y}, {b4.z, b4.w}};
        f32x2 qv2[4];
#pragma unroll
        for (int j = 0; j < 4; ++j) qv2[j] = xv2[j] * xv2[j];
        split8v(xv2, xh[nt], xl[nt]);
        split8v(qv2, qh[nt], ql[nt]);
    }

    __syncthreads();

    // ---- phase 3: m-loop over LDS-resident W ----
    f32x4 rs[4];
#pragma unroll
    for (int nt = 0; nt < 4; ++nt) rs[nt] = (f32x4){0.f, 0.f, 0.f, 0.f};

#pragma unroll 2
    for (int it = 0; it < NITS; ++it) {
        const int base = ((it * 4 + g) * 16 + r15) * 8;
        bf16x8 bh = *(const bf16x8*)&WBH[base];
        bf16x8 ch = *(const bf16x8*)&WCH[base];
        bf16x8 bl = *(const bf16x8*)&WBL[base];
        bf16x8 cl = *(const bf16x8*)&WCL[base];
        const float a2 = A2s[it * 16 + r15];
#pragma unroll
        for (int nt = 0; nt < 4; ++nt) {
            f32x4 acc = (f32x4){a2, a2, a2, a2};   // col=r15 -> a2 const per lane
            acc = __builtin_amdgcn_mfma_f32_16x16x32_bf16(xh[nt], bh, acc, 0, 0, 0);
            acc = __builtin_amdgcn_mfma_f32_16x16x32_bf16(qh[nt], ch, acc, 0, 0, 0);
            acc = __builtin_amdgcn_mfma_f32_16x16x32_bf16(xl[nt], bh, acc, 0, 0, 0);
            acc = __builtin_amdgcn_mfma_f32_16x16x32_bf16(ql[nt], ch, acc, 0, 0, 0);
            acc = __builtin_amdgcn_mfma_f32_16x16x32_bf16(xh[nt], bl, acc, 0, 0, 0);
            acc = __builtin_amdgcn_mfma_f32_16x16x32_bf16(qh[nt], cl, acc, 0, 0, 0);
#pragma unroll
            for (int r = 0; r < 4; ++r) rs[nt][r] += fast_exp2(acc[r]);
        }
    }

    // sum the 16 m-columns (lanes sharing g)
#pragma unroll
    for (int o = 1; o < 16; o <<= 1)
#pragma unroll
        for (int nt = 0; nt < 4; ++nt)
#pragma unroll
            for (int r = 0; r < 4; ++r) rs[nt][r] += __shfl_xor(rs[nt][r], o);

    float* partial = (float*)(wsb + PART_OFF);
    if (r15 == 0) {
#pragma unroll
        for (int nt = 0; nt < 4; ++nt)
            *(f32x4*)(partial + (size_t)blockIdx.y * NS + n0 + nt * 16 + g * 4) = rs[nt];
    }
}

// Merged reduce+flip, vectorized: 8 co-resident blocks x 1024 n (f32x4 per
// thread). dist stays in registers; min/max atomics; counter rendezvous (cnt
// initialized by kde_fused, ordered by kernel boundary); distributed flip.
__global__ __launch_bounds__(256) void reduce_flip(unsigned char* __restrict__ wsb,
                                                   float* __restrict__ out) {
    const f32x4* partial = (const f32x4*)(wsb + PART_OFF);  // [MSPLIT][NS/4]
    unsigned* mm = (unsigned*)(wsb + MM_OFF);
    unsigned* cnt = (unsigned*)(wsb + CNT_OFF);

    const int tid = threadIdx.x;
    const int i = blockIdx.x * 256 + tid;   // f32x4 index
    f32x4 v = (f32x4){0.f, 0.f, 0.f, 0.f};
#pragma unroll
    for (int j = 0; j < MSPLIT; ++j) v += partial[(size_t)j * (NS / 4) + i];

    float mn = fminf(fminf(v[0], v[1]), fminf(v[2], v[3]));
    float mx = fmaxf(fmaxf(v[0], v[1]), fmaxf(v[2], v[3]));
#pragma unroll
    for (int o = 1; o < 64; o <<= 1) {
        mn = fminf(mn, __shfl_xor(mn, o));
        mx = fmaxf(mx, __shfl_xor(mx, o));
    }
    __shared__ float smn[4], smx[4];
    __shared__ float sres[2];
    const int wv = tid >> 6, ln = tid & 63;
    if (ln == 0) { smn[wv] = mn; smx[wv] = mx; }
    __syncthreads();
    if (tid == 0) {
#pragma unroll
        for (int j = 1; j < 4; ++j) {
            mn = fminf(mn, smn[j]);
            mx = fmaxf(mx, smx[j]);
        }
        atomicMin(mm + 0, __float_as_uint(mn));
        atomicMax(mm + 1, __float_as_uint(mx));
        __threadfence();                       // release our atomics
        atomicAdd(cnt, 1u);
        while (__hip_atomic_load(cnt, __ATOMIC_ACQUIRE, __HIP_MEMORY_SCOPE_AGENT)
               < RBLK) {}
        sres[0] = __uint_as_float(
            __hip_atomic_load(mm + 0, __ATOMIC_RELAXED, __HIP_MEMORY_SCOPE_AGENT));
        sres[1] = __uint_as_float(
            __hip_atomic_load(mm + 1, __ATOMIC_RELAXED, __HIP_MEMORY_SCOPE_AGENT));
    }
    __syncthreads();
    const float s = sres[0] + sres[1];
    f32x4 o;
#pragma unroll
    for (int r = 0; r < 4; ++r) o[r] = s - v[r];
    ((f32x4*)out)[i] = o;
}

extern "C" void kernel_launch(void* const* d_in, const int* in_sizes, int n_in,
                              void* d_out, int out_size, void* d_ws, size_t ws_size,
                              hipStream_t stream) {
    const float* samples = (const float*)d_in[0];
    const float* means   = (const float*)d_in[1];
    const float* stds    = (const float*)d_in[2];
    unsigned char* ws = (unsigned char*)d_ws;
    float* out = (float*)d_out;

    kde_fused<<<dim3(NS / 256, MSPLIT), 256, 0, stream>>>(samples, means, stds, ws);
    reduce_flip<<<dim3(RBLK), 256, 0, stream>>>(ws, out);
}

// Round 19
// 18.104 us; speedup vs baseline: 1.2489x; 1.1544x over previous
//
#include <hip/hip_runtime.h>

#define NS 8192
#define MS 2048
#define DD 32
#define MSPLIT 32
#define MCH 64        // m per block
#define NITS 4        // m-tiles per block
#define RBLK 32       // reduce blocks

typedef __attribute__((ext_vector_type(8))) short bf16x8;
typedef __attribute__((ext_vector_type(4))) float f32x4;
typedef unsigned short u16;
typedef unsigned int u32;

// ws byte offsets
#define PART_OFF 0                          // [MSPLIT][NS] f32 (1 MB)
#define MM_OFF   (MSPLIT * NS * 4)          // 2 u32 (min,max bits)
#define CNT_OFF  (MM_OFF + 8)               // 1 u32

__device__ inline float fast_exp2(float x) {
#if __has_builtin(__builtin_amdgcn_exp2f)
    return __builtin_amdgcn_exp2f(x);
#else
    return exp2f(x);
#endif
}
__device__ inline float fast_rcp(float x) {
#if __has_builtin(__builtin_amdgcn_rcpf)
    return __builtin_amdgcn_rcpf(x);   // 1 inst vs ~8 for exact div (R6-validated)
#else
    return 1.0f / x;
#endif
}

__device__ inline u32 cvt_pk_bf16(float a, float b) {
    u32 r;
    asm("v_cvt_pk_bf16_f32 %0, %1, %2" : "=v"(r) : "v"(a), "v"(b));
    return r;
}

// Split 8 floats into hi/lo bf16x8 (RNE). Pack-order safe: W and X use the
// same helper, so MFMA dots pair identical k-elements either way.
__device__ inline void split8(const float* v, bf16x8& hi, bf16x8& lo) {
    union { u32 u[4]; bf16x8 b; } H, L;
#pragma unroll
    for (int j = 0; j < 4; ++j) {
        u32 h = cvt_pk_bf16(v[2 * j], v[2 * j + 1]);
        float ha = __uint_as_float(h << 16);
        float hb = __uint_as_float(h & 0xFFFF0000u);
        L.u[j] = cvt_pk_bf16(v[2 * j] - ha, v[2 * j + 1] - hb);
        H.u[j] = h;
    }
    hi = H.b;
    lo = L.b;
}

// R16 base with ONE structural change: MFMA operands swapped (A=W, B=X) so the
// output has m on ROWS. Each lane then holds 4 m-values in-register:
//   sum over m = 3 in-lane adds + 2 shfl steps (g-bits)  [was 64 shfl + 64 add]
//   a2 init    = one ds_read_b128 (A2s[it*16+g*4..+3] == rows of this lane)
// Fragment construction is identical for A-rows and B-cols ([r15][g*8..]), so
// the swap is layout-safe. Same 6 hi/lo products, same exp count.
__global__ __launch_bounds__(256, 4) void kde_fused(const float* __restrict__ samples,
                                                    const float* __restrict__ means,
                                                    const float* __restrict__ stds,
                                                    unsigned char* __restrict__ wsb) {
    __shared__ u16 WBH[2048], WBL[2048], WCH[2048], WCL[2048];  // [it][g][r15][8]
    __shared__ float A2s[MCH];

    const int t = threadIdx.x;
    const int m0 = blockIdx.y * MCH;
    const float L2E = 1.4426950408889634f;

    if (blockIdx.x == 0 && blockIdx.y == 0 && t == 0) {
        unsigned* mm = (unsigned*)(wsb + MM_OFF);
        mm[0] = 0x7f7fffffu;  // FLT_MAX bits (uint cmp == float cmp, all positive)
        mm[1] = 0u;
        *(unsigned*)(wsb + CNT_OFF) = 0u;
    }

    // ---- phase 1: W chunk -> LDS, one thread per (m_local, 8-d quarter) ----
    {
        const int ml = t >> 2, qd = t & 3;
        const float* mp = means + (size_t)(m0 + ml) * DD + qd * 8;
        const float* vp = stds  + (size_t)(m0 + ml) * DD + qd * 8;
        float4 a4 = *(const float4*)mp, b4 = *(const float4*)(mp + 4);
        float4 c4 = *(const float4*)vp, d4 = *(const float4*)(vp + 4);
        float mu[8] = {a4.x, a4.y, a4.z, a4.w, b4.x, b4.y, b4.z, b4.w};
        float sd[8] = {c4.x, c4.y, c4.z, c4.w, d4.x, d4.y, d4.z, d4.w};
        float Bv[8], Cv[8], a = 0.f;
#pragma unroll
        for (int j = 0; j < 8; ++j) {
            float inv = fast_rcp(sd[j]);
            Bv[j] = L2E * mu[j] * inv;
            Cv[j] = -0.5f * L2E * inv;
            a += mu[j] * mu[j] * inv;
        }
        a += __shfl_xor(a, 1);
        a += __shfl_xor(a, 2);
        if (qd == 0) A2s[ml] = -0.5f * L2E * a - 11.0f;  // -log2(M) folds the mean

        bf16x8 bh, bl, ch, cl;
        split8(Bv, bh, bl);
        split8(Cv, ch, cl);
        const int it = ml >> 4, r15 = ml & 15;
        const int base = ((it * 4 + qd) * 16 + r15) * 8;
        *(bf16x8*)&WBH[base] = bh;
        *(bf16x8*)&WBL[base] = bl;
        *(bf16x8*)&WCH[base] = ch;
        *(bf16x8*)&WCL[base] = cl;
    }

    // ---- phase 2: X fragments straight from samples (all 4 tiles up front) ----
    const int lane = t & 63, wid = t >> 6;
    const int r15 = lane & 15, g = lane >> 4;
    const int n0 = blockIdx.x * 256 + wid * 64;

    bf16x8 xh[4], xl[4], qh[4], ql[4];
#pragma unroll
    for (int nt = 0; nt < 4; ++nt) {
        const float* sp = samples + (size_t)(n0 + nt * 16 + r15) * DD + g * 8;
        float4 a4 = *(const float4*)sp, b4 = *(const float4*)(sp + 4);
        float xv[8] = {a4.x, a4.y, a4.z, a4.w, b4.x, b4.y, b4.z, b4.w};
        float qv[8];
#pragma unroll
        for (int j = 0; j < 8; ++j) qv[j] = xv[j] * xv[j];
        split8(xv, xh[nt], xl[nt]);
        split8(qv, qh[nt], ql[nt]);
    }

    __syncthreads();

    // ---- phase 3: m-loop, D = W·X (m on rows) ----
    float rs[4] = {0.f, 0.f, 0.f, 0.f};

#pragma unroll 2
    for (int it = 0; it < NITS; ++it) {
        const int base = ((it * 4 + g) * 16 + r15) * 8;
        bf16x8 bh = *(const bf16x8*)&WBH[base];
        bf16x8 ch = *(const bf16x8*)&WCH[base];
        bf16x8 bl = *(const bf16x8*)&WBL[base];
        bf16x8 cl = *(const bf16x8*)&WCL[base];
        // rows of this lane are m = it*16 + g*4 + r  ->  16B-aligned f32x4
        const f32x4 a2v = *(const f32x4*)&A2s[it * 16 + g * 4];
#pragma unroll
        for (int nt = 0; nt < 4; ++nt) {
            f32x4 acc = a2v;
            acc = __builtin_amdgcn_mfma_f32_16x16x32_bf16(bh, xh[nt], acc, 0, 0, 0);
            acc = __builtin_amdgcn_mfma_f32_16x16x32_bf16(ch, qh[nt], acc, 0, 0, 0);
            acc = __builtin_amdgcn_mfma_f32_16x16x32_bf16(bh, xl[nt], acc, 0, 0, 0);
            acc = __builtin_amdgcn_mfma_f32_16x16x32_bf16(ch, ql[nt], acc, 0, 0, 0);
            acc = __builtin_amdgcn_mfma_f32_16x16x32_bf16(bl, xh[nt], acc, 0, 0, 0);
            acc = __builtin_amdgcn_mfma_f32_16x16x32_bf16(cl, qh[nt], acc, 0, 0, 0);
            rs[nt] += (fast_exp2(acc[0]) + fast_exp2(acc[1]))
                    + (fast_exp2(acc[2]) + fast_exp2(acc[3]));
        }
    }

    // sum the 4 g-groups (m-row blocks): 2 shfl steps, all lanes get the total
#pragma unroll
    for (int nt = 0; nt < 4; ++nt) {
        rs[nt] += __shfl_xor(rs[nt], 16);
        rs[nt] += __shfl_xor(rs[nt], 32);
    }

    float* partial = (float*)(wsb + PART_OFF);
    if (g == 0) {   // lanes 0..15: n = n0 + nt*16 + r15, 64B coalesced per nt
#pragma unroll
        for (int nt = 0; nt < 4; ++nt)
            partial[(size_t)blockIdx.y * NS + n0 + nt * 16 + r15] = rs[nt];
    }
}

// Merged reduce+flip (R16, proven): 32 co-resident blocks; dist in registers;
// min/max atomics; counter rendezvous (cnt initialized by kde_fused, ordered
// by the kernel boundary); distributed flip.
__global__ __launch_bounds__(256) void reduce_flip(unsigned char* __restrict__ wsb,
                                                   float* __restrict__ out) {
    const float* partial = (const float*)(wsb + PART_OFF);
    unsigned* mm = (unsigned*)(wsb + MM_OFF);
    unsigned* cnt = (unsigned*)(wsb + CNT_OFF);

    const int tid = threadIdx.x;
    const int n = blockIdx.x * 256 + tid;
    float v = 0.f;
#pragma unroll
    for (int j = 0; j < MSPLIT; ++j) v += partial[(size_t)j * NS + n];

    float mn = v, mx = v;
#pragma unroll
    for (int o = 1; o < 64; o <<= 1) {
        mn = fminf(mn, __shfl_xor(mn, o));
        mx = fmaxf(mx, __shfl_xor(mx, o));
    }
    __shared__ float smn[4], smx[4];
    __shared__ float sres[2];
    const int wv = tid >> 6, ln = tid & 63;
    if (ln == 0) { smn[wv] = mn; smx[wv] = mx; }
    __syncthreads();
    if (tid == 0) {
#pragma unroll
        for (int j = 1; j < 4; ++j) {
            mn = fminf(mn, smn[j]);
            mx = fmaxf(mx, smx[j]);
        }
        atomicMin(mm + 0, __float_as_uint(mn));
        atomicMax(mm + 1, __float_as_uint(mx));
        __threadfence();                       // release our atomics
        atomicAdd(cnt, 1u);
        while (__hip_atomic_load(cnt, __ATOMIC_ACQUIRE, __HIP_MEMORY_SCOPE_AGENT)
               < RBLK) {}
        sres[0] = __uint_as_float(
            __hip_atomic_load(mm + 0, __ATOMIC_RELAXED, __HIP_MEMORY_SCOPE_AGENT));
        sres[1] = __uint_as_float(
            __hip_atomic_load(mm + 1, __ATOMIC_RELAXED, __HIP_MEMORY_SCOPE_AGENT));
    }
    __syncthreads();
    out[n] = sres[1] + sres[0] - v;
}

extern "C" void kernel_launch(void* const* d_in, const int* in_sizes, int n_in,
                              void* d_out, int out_size, void* d_ws, size_t ws_size,
                              hipStream_t stream) {
    const float* samples = (const float*)d_in[0];
    const float* means   = (const float*)d_in[1];
    const float* stds    = (const float*)d_in[2];
    unsigned char* ws = (unsigned char*)d_ws;
    float* out = (float*)d_out;

    kde_fused<<<dim3(NS / 256, MSPLIT), 256, 0, stream>>>(samples, means, stds, ws);
    reduce_flip<<<dim3(RBLK), 256, 0, stream>>>(ws, out);
}

// Round 20
// 17.138 us; speedup vs baseline: 1.3193x; 1.0564x over previous
//
#include <hip/hip_runtime.h>

#define NS 8192
#define MS 2048
#define DD 32
#define MSPLIT 16
#define MCH 128       // m per block
#define NITS 8        // m-tiles per block
#define RBLK 32       // reduce blocks

typedef __attribute__((ext_vector_type(8))) short bf16x8;
typedef __attribute__((ext_vector_type(4))) float f32x4;
typedef unsigned short u16;
typedef unsigned int u32;

// ws byte offsets
#define PART_OFF 0                          // [MSPLIT][NS] f32 (512 KB)
#define MM_OFF   (MSPLIT * NS * 4)          // 2 u32 (min,max bits)
#define CNT_OFF  (MM_OFF + 8)               // 1 u32

__device__ inline float fast_exp2(float x) {
#if __has_builtin(__builtin_amdgcn_exp2f)
    return __builtin_amdgcn_exp2f(x);
#else
    return exp2f(x);
#endif
}
__device__ inline float fast_rcp(float x) {
#if __has_builtin(__builtin_amdgcn_rcpf)
    return __builtin_amdgcn_rcpf(x);   // 1 inst vs ~8 for exact div (R6-validated)
#else
    return 1.0f / x;
#endif
}

__device__ inline u32 cvt_pk_bf16(float a, float b) {
    u32 r;
    asm("v_cvt_pk_bf16_f32 %0, %1, %2" : "=v"(r) : "v"(a), "v"(b));
    return r;
}

// Split 8 floats into hi/lo bf16x8 (RNE). Pack-order safe: W and X use the
// same helper, so MFMA dots pair identical k-elements either way.
__device__ inline void split8(const float* v, bf16x8& hi, bf16x8& lo) {
    union { u32 u[4]; bf16x8 b; } H, L;
#pragma unroll
    for (int j = 0; j < 4; ++j) {
        u32 h = cvt_pk_bf16(v[2 * j], v[2 * j + 1]);
        float ha = __uint_as_float(h << 16);
        float hb = __uint_as_float(h & 0xFFFF0000u);
        L.u[j] = cvt_pk_bf16(v[2 * j] - ha, v[2 * j + 1] - hb);
        H.u[j] = h;
    }
    hi = H.b;
    lo = L.b;
}

// R19 body (operand-swapped, proven 18.1us) with MSPLIT 16: each block sweeps
// 128 m against its converted X -> total X-conversion work halves (it was 32x
// redundant across mb-blocks), partial traffic halves. Occupancy 2 blocks/CU;
// the m-loop's 4 independent nt chains + unroll-2 must cover the lower TLP.
__global__ __launch_bounds__(256, 4) void kde_fused(const float* __restrict__ samples,
                                                    const float* __restrict__ means,
                                                    const float* __restrict__ stds,
                                                    unsigned char* __restrict__ wsb) {
    __shared__ u16 WBH[NITS * 512], WBL[NITS * 512], WCH[NITS * 512], WCL[NITS * 512];
    __shared__ float A2s[MCH];

    const int t = threadIdx.x;
    const int m0 = blockIdx.y * MCH;
    const float L2E = 1.4426950408889634f;

    if (blockIdx.x == 0 && blockIdx.y == 0 && t == 0) {
        unsigned* mm = (unsigned*)(wsb + MM_OFF);
        mm[0] = 0x7f7fffffu;  // FLT_MAX bits (uint cmp == float cmp, all positive)
        mm[1] = 0u;
        *(unsigned*)(wsb + CNT_OFF) = 0u;
    }

    // ---- phase 1: W chunk -> LDS, one thread per (m_local, 16-d half) ----
    {
        const int ml = t >> 1, half = t & 1, d0 = half * 16;
        const float* mp = means + (size_t)(m0 + ml) * DD + d0;
        const float* vp = stds  + (size_t)(m0 + ml) * DD + d0;
        float mu[16], sd[16];
#pragma unroll
        for (int j = 0; j < 4; ++j) {
            float4 a4 = *(const float4*)(mp + j * 4);
            float4 c4 = *(const float4*)(vp + j * 4);
            mu[j*4+0]=a4.x; mu[j*4+1]=a4.y; mu[j*4+2]=a4.z; mu[j*4+3]=a4.w;
            sd[j*4+0]=c4.x; sd[j*4+1]=c4.y; sd[j*4+2]=c4.z; sd[j*4+3]=c4.w;
        }
        float Bv[16], Cv[16], a = 0.f;
#pragma unroll
        for (int j = 0; j < 16; ++j) {
            float inv = fast_rcp(sd[j]);
            Bv[j] = L2E * mu[j] * inv;
            Cv[j] = -0.5f * L2E * inv;
            a += mu[j] * mu[j] * inv;
        }
        a += __shfl_xor(a, 1);   // combine the two 16-d halves of row ml
        if (half == 0) A2s[ml] = -0.5f * L2E * a - 11.0f;  // -log2(M) folds mean

        const int it = ml >> 4, r15 = ml & 15;
#pragma unroll
        for (int r2 = 0; r2 < 2; ++r2) {
            bf16x8 bh, bl, ch, cl;
            split8(Bv + r2 * 8, bh, bl);
            split8(Cv + r2 * 8, ch, cl);
            const int qd = half * 2 + r2;
            const int base = ((it * 4 + qd) * 16 + r15) * 8;
            *(bf16x8*)&WBH[base] = bh;
            *(bf16x8*)&WBL[base] = bl;
            *(bf16x8*)&WCH[base] = ch;
            *(bf16x8*)&WCL[base] = cl;
        }
    }

    // ---- phase 2: X fragments straight from samples (all 4 tiles up front) ----
    const int lane = t & 63, wid = t >> 6;
    const int r15 = lane & 15, g = lane >> 4;
    const int n0 = blockIdx.x * 256 + wid * 64;

    bf16x8 xh[4], xl[4], qh[4], ql[4];
#pragma unroll
    for (int nt = 0; nt < 4; ++nt) {
        const float* sp = samples + (size_t)(n0 + nt * 16 + r15) * DD + g * 8;
        float4 a4 = *(const float4*)sp, b4 = *(const float4*)(sp + 4);
        float xv[8] = {a4.x, a4.y, a4.z, a4.w, b4.x, b4.y, b4.z, b4.w};
        float qv[8];
#pragma unroll
        for (int j = 0; j < 8; ++j) qv[j] = xv[j] * xv[j];
        split8(xv, xh[nt], xl[nt]);
        split8(qv, qh[nt], ql[nt]);
    }

    __syncthreads();

    // ---- phase 3: m-loop, D = W·X (m on rows) ----
    float rs[4] = {0.f, 0.f, 0.f, 0.f};

#pragma unroll 2
    for (int it = 0; it < NITS; ++it) {
        const int base = ((it * 4 + g) * 16 + r15) * 8;
        bf16x8 bh = *(const bf16x8*)&WBH[base];
        bf16x8 ch = *(const bf16x8*)&WCH[base];
        bf16x8 bl = *(const bf16x8*)&WBL[base];
        bf16x8 cl = *(const bf16x8*)&WCL[base];
        // rows of this lane are m = it*16 + g*4 + r  ->  16B-aligned f32x4
        const f32x4 a2v = *(const f32x4*)&A2s[it * 16 + g * 4];
#pragma unroll
        for (int nt = 0; nt < 4; ++nt) {
            f32x4 acc = a2v;
            acc = __builtin_amdgcn_mfma_f32_16x16x32_bf16(bh, xh[nt], acc, 0, 0, 0);
            acc = __builtin_amdgcn_mfma_f32_16x16x32_bf16(ch, qh[nt], acc, 0, 0, 0);
            acc = __builtin_amdgcn_mfma_f32_16x16x32_bf16(bh, xl[nt], acc, 0, 0, 0);
            acc = __builtin_amdgcn_mfma_f32_16x16x32_bf16(ch, ql[nt], acc, 0, 0, 0);
            acc = __builtin_amdgcn_mfma_f32_16x16x32_bf16(bl, xh[nt], acc, 0, 0, 0);
            acc = __builtin_amdgcn_mfma_f32_16x16x32_bf16(cl, qh[nt], acc, 0, 0, 0);
            rs[nt] += (fast_exp2(acc[0]) + fast_exp2(acc[1]))
                    + (fast_exp2(acc[2]) + fast_exp2(acc[3]));
        }
    }

    // sum the 4 g-groups (m-row blocks): 2 shfl steps
#pragma unroll
    for (int nt = 0; nt < 4; ++nt) {
        rs[nt] += __shfl_xor(rs[nt], 16);
        rs[nt] += __shfl_xor(rs[nt], 32);
    }

    float* partial = (float*)(wsb + PART_OFF);
    if (g == 0) {   // lanes 0..15: n = n0 + nt*16 + r15, 64B coalesced per nt
#pragma unroll
        for (int nt = 0; nt < 4; ++nt)
            partial[(size_t)blockIdx.y * NS + n0 + nt * 16 + r15] = rs[nt];
    }
}

// Merged reduce+flip (R16, proven): 32 co-resident blocks; dist in registers;
// min/max atomics; counter rendezvous (cnt initialized by kde_fused, ordered
// by the kernel boundary); distributed flip.
__global__ __launch_bounds__(256) void reduce_flip(unsigned char* __restrict__ wsb,
                                                   float* __restrict__ out) {
    const float* partial = (const float*)(wsb + PART_OFF);
    unsigned* mm = (unsigned*)(wsb + MM_OFF);
    unsigned* cnt = (unsigned*)(wsb + CNT_OFF);

    const int tid = threadIdx.x;
    const int n = blockIdx.x * 256 + tid;
    float v = 0.f;
#pragma unroll
    for (int j = 0; j < MSPLIT; ++j) v += partial[(size_t)j * NS + n];

    float mn = v, mx = v;
#pragma unroll
    for (int o = 1; o < 64; o <<= 1) {
        mn = fminf(mn, __shfl_xor(mn, o));
        mx = fmaxf(mx, __shfl_xor(mx, o));
    }
    __shared__ float smn[4], smx[4];
    __shared__ float sres[2];
    const int wv = tid >> 6, ln = tid & 63;
    if (ln == 0) { smn[wv] = mn; smx[wv] = mx; }
    __syncthreads();
    if (tid == 0) {
#pragma unroll
        for (int j = 1; j < 4; ++j) {
            mn = fminf(mn, smn[j]);
            mx = fmaxf(mx, smx[j]);
        }
        atomicMin(mm + 0, __float_as_uint(mn));
        atomicMax(mm + 1, __float_as_uint(mx));
        __threadfence();                       // release our atomics
        atomicAdd(cnt, 1u);
        while (__hip_atomic_load(cnt, __ATOMIC_ACQUIRE, __HIP_MEMORY_SCOPE_AGENT)
               < RBLK) {}
        sres[0] = __uint_as_float(
            __hip_atomic_load(mm + 0, __ATOMIC_RELAXED, __HIP_MEMORY_SCOPE_AGENT));
        sres[1] = __uint_as_float(
            __hip_atomic_load(mm + 1, __ATOMIC_RELAXED, __HIP_MEMORY_SCOPE_AGENT));
    }
    __syncthreads();
    out[n] = sres[1] + sres[0] - v;
}

extern "C" void kernel_launch(void* const* d_in, const int* in_sizes, int n_in,
                              void* d_out, int out_size, void* d_ws, size_t ws_size,
                              hipStream_t stream) {
    const float* samples = (const float*)d_in[0];
    const float* means   = (const float*)d_in[1];
    const float* stds    = (const float*)d_in[2];
    unsigned char* ws = (unsigned char*)d_ws;
    float* out = (float*)d_out;

    kde_fused<<<dim3(NS / 256, MSPLIT), 256, 0, stream>>>(samples, means, stds, ws);
    reduce_flip<<<dim3(RBLK), 256, 0, stream>>>(ws, out);
}